// Round 9
// baseline (1651.859 us; speedup 1.0000x reference)
//
#include <hip/hip_runtime.h>
#include <stdint.h>

#define TT 512

typedef __fp16   f16x8  __attribute__((ext_vector_type(8)));
typedef float    f32x4  __attribute__((ext_vector_type(4)));
typedef __fp16   fp16x2 __attribute__((ext_vector_type(2)));
typedef uint32_t u32x2  __attribute__((ext_vector_type(2)));

__device__ __forceinline__ float sigm(float x) {
    float e = __builtin_amdgcn_exp2f(-1.4426950408889634f * x);
    return __builtin_amdgcn_rcpf(1.0f + e);
}
__device__ __forceinline__ f32x4 mfma16(f16x8 a, f16x8 b, f32x4 c) {
    return __builtin_amdgcn_mfma_f32_16x16x32_f16(a, b, c, 0, 0, 0);
}
__device__ __forceinline__ uint32_t pkf16(float a, float b) {
    fp16x2 h = __builtin_amdgcn_cvt_pkrtz(a, b);
    return __builtin_bit_cast(uint32_t, h);
}

#define REP16(M) M(0)M(1)M(2)M(3)M(4)M(5)M(6)M(7)M(8)M(9)M(10)M(11)M(12)M(13)M(14)M(15)

// A-operand gather (weights TRANSPOSED, z^T form): A[m=16T+l15][k=32F+8q+j] = SRC[k][16T+l15]
#define GA(SRC, T, F) (f16x8){ \
  (__fp16)(SRC)[(32*(F)+8*quad+0)*256 + 16*(T)+l15], \
  (__fp16)(SRC)[(32*(F)+8*quad+1)*256 + 16*(T)+l15], \
  (__fp16)(SRC)[(32*(F)+8*quad+2)*256 + 16*(T)+l15], \
  (__fp16)(SRC)[(32*(F)+8*quad+3)*256 + 16*(T)+l15], \
  (__fp16)(SRC)[(32*(F)+8*quad+4)*256 + 16*(T)+l15], \
  (__fp16)(SRC)[(32*(F)+8*quad+5)*256 + 16*(T)+l15], \
  (__fp16)(SRC)[(32*(F)+8*quad+6)*256 + 16*(T)+l15], \
  (__fp16)(SRC)[(32*(F)+8*quad+7)*256 + 16*(T)+l15] }

// Named scalars only (R1-R3: arrays -> SROA scratch). U/Wx A-frags + f32 bias resident.
#define DECLT(T) f16x8 uA##T##_0, uA##T##_1, wA##T##_0, wA##T##_1; f32x4 bias##T;
#define LOADT(T) { \
  uA##T##_0 = GA(Uw, T, 0); uA##T##_1 = GA(Uw, T, 1); \
  bias##T = (f32x4){ bw_[16*(T)+4*quad+0], bw_[16*(T)+4*quad+1], \
                     bw_[16*(T)+4*quad+2], bw_[16*(T)+4*quad+3] }; \
  if (l > 0) { wA##T##_0 = GA(Wsrc, T, 0); wA##T##_1 = GA(Wsrc, T, 1); } \
  else { /* wave 0: stash fp32 Wx0 column scalars in the (otherwise unused) wA regs */ \
    wA##T##_0 = __builtin_bit_cast(f16x8, (f32x4){ Wx0[16*(T)+4*quad+0], Wx0[16*(T)+4*quad+1], \
                                                   Wx0[16*(T)+4*quad+2], Wx0[16*(T)+4*quad+3] }); \
    wA##T##_1 = wA##T##_0; } }

#define DECLA(T) f32x4 acc##T;
// R8 post-mortem: per-tile 4-deep dependent MFMA chains serialize on MFMA latency.
// R9: STAGE-MAJOR emission — all 16 tiles per k-stage, adjacent instrs independent.
// W-side first (producer data has a full step of slack; bias rides its C operand),
// U-side last (own-h is the zero-slack dependency).
#define MW0(T) acc##T = mfma16(wA##T##_0, xB0, bias##T);
#define MW1(T) acc##T = mfma16(wA##T##_1, xB1, acc##T);
#define MX0(T) acc##T = bias##T + __builtin_bit_cast(f32x4, wA##T##_0) * xv4;
#define MU0(T) acc##T = mfma16(uA##T##_0, hB0, acc##T);
#define MU1(T) acc##T = mfma16(uA##T##_1, hB1, acc##T);

// D layout: m = zr = 16T + 4*quad + r, n = row = l15. Gates: zr = u + 64g -> tiles T0,T0+4,T0+8,T0+12
#define GATE4(T0, TF, TG, TO) { \
  f32x4 hv_; \
  _Pragma("unroll") \
  for (int r = 0; r < 4; ++r) { \
    float cv = sigm(acc##TF[r]) * cst##T0[r] + sigm(acc##T0[r]) * fmaxf(acc##TG[r], 0.f); \
    cst##T0[r] = cv; \
    hv_[r] = sigm(acc##TO[r]) * fmaxf(cv, 0.f); \
  } \
  u32x2 pv_ = { pkf16(hv_[0], hv_[1]), pkf16(hv_[2], hv_[3]) }; \
  *(u32x2*)(hwl + 16*(T0)) = pv_; \
  if (l == 3 && t == TT - 1) hK##T0 = hv_; }

// 64 blocks x 256 threads; block = 16 batch rows; 4 waves = 4 layers (whole layer per wave).
// Recurrence INTRA-WAVE (lgkm-ordered LDS roundtrip); layer handoff via 4-deep slot buffer
// + cached progress flags (common case: zero sync LDS ops). waves_per_eu(1,1): 512-reg budget.
__global__ __launch_bounds__(256)
__attribute__((amdgpu_waves_per_eu(1, 1)))
void lstm_wavepipe(
    const float* __restrict__ x,
    const float* __restrict__ Wx0, const float* __restrict__ U0, const float* __restrict__ b0,
    const float* __restrict__ Wx1, const float* __restrict__ U1, const float* __restrict__ b1,
    const float* __restrict__ Wx2, const float* __restrict__ U2, const float* __restrict__ b2,
    const float* __restrict__ Wx3, const float* __restrict__ U3, const float* __restrict__ b3,
    const float* __restrict__ Wd,  const float* __restrict__ bd,
    float* __restrict__ out)
{
    // dynamic LDS (dwords): hbuf f16 [0,9216) | x_s f32 [9216,17920) | flags [17920,17924)
    extern __shared__ uint32_t smem[];
    __fp16*       hbuf = (__fp16*)smem;            // [l][slot4][row 16][unit 64 pad 72] f16
    float*        x_s  = (float*)(smem + 9216);    // [t][17] padded
    volatile int* vf   = (volatile int*)(smem + 17920);

    const int tid  = threadIdx.x;
    const int lane = tid & 63;
    const int l15  = lane & 15;
    const int quad = lane >> 4;
    const int l    = tid >> 6;                     // wave = layer
    const int b0i  = blockIdx.x * 16;

    // ---- staging ----
    for (int i = tid; i < 9216; i += 256) smem[i] = 0;   // zero all h slots
    if (tid < 4) vf[tid] = 0;
    for (int i = tid; i < 16 * TT; i += 256) {
        int row = i >> 9, t_ = i & (TT - 1);
        x_s[t_ * 17 + row] = x[(b0i + row) * TT + t_];
    }

    const float* Uw   = (l == 0) ? U0 : (l == 1) ? U1 : (l == 2) ? U2 : U3;
    const float* bw_  = (l == 0) ? b0 : (l == 1) ? b1 : (l == 2) ? b2 : b3;
    const float* Wsrc = (l == 1) ? Wx1 : (l == 2) ? Wx2 : (l == 3) ? Wx3 : U0;

    REP16(DECLT)
    REP16(LOADT)

    f32x4 cst0 = {0,0,0,0}, cst1 = {0,0,0,0}, cst2 = {0,0,0,0}, cst3 = {0,0,0,0};
    f32x4 hK0 = {0,0,0,0}, hK1 = {0,0,0,0}, hK2 = {0,0,0,0}, hK3 = {0,0,0,0};

    __fp16* hb_l  = hbuf + l * 4608;               // own layer buffer (4 slots x 1152)
    __fp16* hb_in = hbuf + (l > 0 ? (l - 1) * 4608 : 0);

    int pseen = 0, cseen = 0;                      // cached flag values

    __syncthreads();                               // the only barrier

    for (int t = 0; t < TT; ++t) {
        const int sr = (t - 1) & 3, sw = t & 3;

        // own h[t-1] read issued FIRST: its latency overlaps the spin/x-read/W-issue
        const __fp16* hown = hb_l + sr * 1152 + l15 * 72 + 8 * quad;
        f16x8 hB0 = *(const f16x8*)(hown);
        f16x8 hB1 = *(const f16x8*)(hown + 32);

        REP16(DECLA)
        if (l > 0) {
            // producer-ready: need h^(l-1)[t]; cached flag makes this free in steady state
            if (pseen < t + 1) { do { pseen = vf[l - 1]; } while (pseen < t + 1); }
            __threadfence_block();                 // acquire
            const __fp16* hin = hb_in + sw * 1152 + l15 * 72 + 8 * quad;
            f16x8 xB0 = *(const f16x8*)(hin);
            f16x8 xB1 = *(const f16x8*)(hin + 32);
            REP16(MW0)
            REP16(MW1)
        } else {
            float xv = x_s[t * 17 + l15];
            f32x4 xv4 = {xv, xv, xv, xv};
            REP16(MX0)
        }
        REP16(MU0)
        REP16(MU1)

        // back-pressure: writing slot sw overwrites h[t-4]; consumer must be past t-4
        if (l < 3) {
            if (cseen < t - 3) { do { cseen = vf[l + 1]; } while (cseen < t - 3); }
        }

        // gates + publish h (lane holds row=l15, units 16*T0+4*quad+r)
        __fp16* hwl = hb_l + sw * 1152 + l15 * 72 + 4 * quad;
        GATE4(0, 4,  8, 12)
        GATE4(1, 5,  9, 13)
        GATE4(2, 6, 10, 14)
        GATE4(3, 7, 11, 15)

        __threadfence_block();                     // release (drain h writes)
        vf[l] = t + 1;
    }

    // dense epilogue: wave 3 holds h[511] in hK regs (f32, pre-quant)
    if (l == 3) {
        float p = 0.f;
        #define EPI(T0) { f32x4 wdv = (f32x4){ Wd[16*(T0)+4*quad+0], Wd[16*(T0)+4*quad+1], \
                                               Wd[16*(T0)+4*quad+2], Wd[16*(T0)+4*quad+3] }; \
            p += hK##T0[0]*wdv[0] + hK##T0[1]*wdv[1] + hK##T0[2]*wdv[2] + hK##T0[3]*wdv[3]; }
        EPI(0) EPI(1) EPI(2) EPI(3)
        p += __shfl_down(p, 32, 64);
        p += __shfl_down(p, 16, 64);
        if (lane < 16) out[b0i + lane] = p + bd[0];
    }
}

extern "C" void kernel_launch(void* const* d_in, const int* in_sizes, int n_in,
                              void* d_out, int out_size, void* d_ws, size_t ws_size,
                              hipStream_t stream) {
    const float* x   = (const float*)d_in[0];
    const float* Wx0 = (const float*)d_in[1];
    const float* U0  = (const float*)d_in[2];
    const float* b0  = (const float*)d_in[3];
    const float* Wx1 = (const float*)d_in[4];
    const float* U1  = (const float*)d_in[5];
    const float* b1  = (const float*)d_in[6];
    const float* Wx2 = (const float*)d_in[7];
    const float* U2  = (const float*)d_in[8];
    const float* b2  = (const float*)d_in[9];
    const float* Wx3 = (const float*)d_in[10];
    const float* U3  = (const float*)d_in[11];
    const float* b3  = (const float*)d_in[12];
    const float* Wd  = (const float*)d_in[13];
    const float* bd  = (const float*)d_in[14];
    float* out = (float*)d_out;

    static const int kLds = 17924 * 4;   // 71696 B dynamic LDS
    (void)hipFuncSetAttribute((const void*)lstm_wavepipe,
                              hipFuncAttributeMaxDynamicSharedMemorySize, kLds);
    hipLaunchKernelGGL(lstm_wavepipe, dim3(64), dim3(256), kLds, stream,
                       x, Wx0, U0, b0, Wx1, U1, b1, Wx2, U2, b2, Wx3, U3, b3,
                       Wd, bd, out);
}

// Round 10
// 758.474 us; speedup vs baseline: 2.1779x; 2.1779x over previous
//
#include <hip/hip_runtime.h>
#include <stdint.h>

#define TT 512

typedef __fp16   f16x8  __attribute__((ext_vector_type(8)));
typedef float    f32x4  __attribute__((ext_vector_type(4)));
typedef __fp16   fp16x2 __attribute__((ext_vector_type(2)));
typedef uint32_t u32x2  __attribute__((ext_vector_type(2)));

__device__ __forceinline__ f32x4 mfma16(f16x8 a, f16x8 b, f32x4 c) {
    return __builtin_amdgcn_mfma_f32_16x16x32_f16(a, b, c, 0, 0, 0);
}
__device__ __forceinline__ uint32_t pkf16(float a, float b) {
    fp16x2 h = __builtin_amdgcn_cvt_pkrtz(a, b);
    return __builtin_bit_cast(uint32_t, h);
}

#define REP8(M) M(0)M(1)M(2)M(3)M(4)M(5)M(6)M(7)

// A-operand gather (weights transposed, z^T form): A[m=16T+l15][k=32F+8q+j] = SRC[k][16T+l15]
#define GA(SRC, T, F) (f16x8){ \
  (__fp16)(SRC)[(32*(F)+8*quad+0)*256 + 16*(T)+l15], \
  (__fp16)(SRC)[(32*(F)+8*quad+1)*256 + 16*(T)+l15], \
  (__fp16)(SRC)[(32*(F)+8*quad+2)*256 + 16*(T)+l15], \
  (__fp16)(SRC)[(32*(F)+8*quad+3)*256 + 16*(T)+l15], \
  (__fp16)(SRC)[(32*(F)+8*quad+4)*256 + 16*(T)+l15], \
  (__fp16)(SRC)[(32*(F)+8*quad+5)*256 + 16*(T)+l15], \
  (__fp16)(SRC)[(32*(F)+8*quad+6)*256 + 16*(T)+l15], \
  (__fp16)(SRC)[(32*(F)+8*quad+7)*256 + 16*(T)+l15] }

// Wave (l,h) owns zcols {64g + 32h + 16q' .. +15}: local j = 2g+q' -> global tile:
#define DECLT(j) f16x8 uA##j##_0, uA##j##_1, wA##j##_0, wA##j##_1; f32x4 bias##j;
#define LOADT(j) { \
  const int Tg_ = ((j)>>1)*4 + 2*h + ((j)&1); \
  uA##j##_0 = GA(Uw, Tg_, 0); uA##j##_1 = GA(Uw, Tg_, 1); \
  bias##j = (f32x4){ bw_[16*Tg_ + 4*quad + 0], bw_[16*Tg_ + 4*quad + 1], \
                     bw_[16*Tg_ + 4*quad + 2], bw_[16*Tg_ + 4*quad + 3] }; \
  if (l > 0) { wA##j##_0 = GA(Wsrc, Tg_, 0); wA##j##_1 = GA(Wsrc, Tg_, 1); } \
  else { wA##j##_0 = __builtin_bit_cast(f16x8, (f32x4){ \
           Wx0[16*Tg_+4*quad+0], Wx0[16*Tg_+4*quad+1], \
           Wx0[16*Tg_+4*quad+2], Wx0[16*Tg_+4*quad+3] }); \
         wA##j##_1 = wA##j##_0; } }

#define DECLA(j) f32x4 acc##j = {0.f, 0.f, 0.f, 0.f};
// U-side: the ONLY MFMAs on the recurrence chain (acc already holds bias + W-side).
#define MU0(j) acc##j = mfma16(uA##j##_0, hB0, acc##j);
#define MU1(j) acc##j = mfma16(uA##j##_1, hB1, acc##j);
// W-side prefetch for step t+1 (skew-2: producer data ready a step early) — off-chain.
#define MW0(j) acc##j = mfma16(wA##j##_0, xBn0, bias##j);
#define MW1(j) acc##j = mfma16(wA##j##_1, xBn1, acc##j);
#define MX(j)  acc##j = bias##j + __builtin_bit_cast(f32x4, wA##j##_0) * xvn4;

#define PREFW(slot) { \
  const __fp16* xp_ = hb_in + (slot)*1152 + l15*72 + 8*quad; \
  f16x8 xBn0 = *(const f16x8*)xp_; \
  f16x8 xBn1 = *(const f16x8*)(xp_ + 32); \
  REP8(MW0) REP8(MW1) }
#define PREFX(tt) { \
  float xv_ = xs[(tt)*17 + l15]; \
  f32x4 xvn4 = {xv_, xv_, xv_, xv_}; \
  REP8(MX) }

// Batched gates: all exps issued together, then all rcps (throughput-bound bursts,
// not 8 serial sigmoid chains). D layout: lane holds units 16T+4quad+r at row l15.
#define GATES(qp, Ai, Af, Ag, Ao, CST, SAVEK, HK) { \
  f32x4 ei_, ef_, eo_; \
  _Pragma("unroll") \
  for (int r_ = 0; r_ < 4; ++r_) { \
    ei_[r_] = __builtin_amdgcn_exp2f(-1.4426950408889634f * Ai[r_]); \
    ef_[r_] = __builtin_amdgcn_exp2f(-1.4426950408889634f * Af[r_]); \
    eo_[r_] = __builtin_amdgcn_exp2f(-1.4426950408889634f * Ao[r_]); \
  } \
  f32x4 hv_; \
  _Pragma("unroll") \
  for (int r_ = 0; r_ < 4; ++r_) { \
    float si_ = __builtin_amdgcn_rcpf(1.0f + ei_[r_]); \
    float sf_ = __builtin_amdgcn_rcpf(1.0f + ef_[r_]); \
    float so_ = __builtin_amdgcn_rcpf(1.0f + eo_[r_]); \
    float cv_ = sf_ * CST[r_] + si_ * fmaxf(Ag[r_], 0.f); \
    CST[r_] = cv_; \
    hv_[r_] = so_ * fmaxf(cv_, 0.f); \
  } \
  u32x2 pv_ = { pkf16(hv_[0], hv_[1]), pkf16(hv_[2], hv_[3]) }; \
  *(u32x2*)(hw_ + 16*(qp)) = pv_; \
  if (SAVEK) HK = hv_; }

// 64 blocks x 512 threads; block = 16 batch rows; 8 waves = 4 layers x 2 unit-halves.
// Skew-2 layer pipeline (layer l at t = s-2l): W-side MFMAs for t+1 run AFTER gates of t,
// filling the stall shadow; recurrence chain = hB-read -> 16 U-MFMA -> gates -> h-write.
// One barrier/step. One 4-deep h slot buffer per layer serves own-read + consumer-read.
// 512thr + waves_per_eu(2,2) = 256-VGPR budget (R7 proved ~252 fits; R9's 16-tile
// stage-major spilled at the cap — reverted).
__global__ __launch_bounds__(512)
__attribute__((amdgpu_waves_per_eu(2, 2)))
void lstm_pipe(
    const float* __restrict__ x,
    const float* __restrict__ Wx0, const float* __restrict__ U0, const float* __restrict__ b0,
    const float* __restrict__ Wx1, const float* __restrict__ U1, const float* __restrict__ b1,
    const float* __restrict__ Wx2, const float* __restrict__ U2, const float* __restrict__ b2,
    const float* __restrict__ Wx3, const float* __restrict__ U3, const float* __restrict__ b3,
    const float* __restrict__ Wd,  const float* __restrict__ bd,
    float* __restrict__ out)
{
    // dwords: hbuf f16 [0,9216) | x_s f32 [9216,17920) | red f32 [17920,17952)
    extern __shared__ uint32_t smem[];
    __fp16* hb16 = (__fp16*)smem;              // [l][slot4][row 16][unit 64 pad 72]
    float*  xs   = (float*)(smem + 9216);      // [t][17]
    float*  red  = (float*)(smem + 17920);     // [2][16] epilogue partials

    const int tid  = threadIdx.x;
    const int lane = tid & 63;
    const int l15  = lane & 15;
    const int quad = lane >> 4;
    const int wv   = tid >> 6;
    const int l    = wv >> 1;                  // layer
    const int h    = wv & 1;                   // unit-half
    const int b0i  = blockIdx.x * 16;

    // ---- staging ----
    for (int i = tid; i < 9216; i += 512) smem[i] = 0;       // zero all h slots
    for (int i = tid; i < 16 * TT; i += 512) {
        int row = i >> 9, t_ = i & (TT - 1);
        xs[t_ * 17 + row] = x[(b0i + row) * TT + t_];
    }

    const float* Uw   = (l == 0) ? U0 : (l == 1) ? U1 : (l == 2) ? U2 : U3;
    const float* bw_  = (l == 0) ? b0 : (l == 1) ? b1 : (l == 2) ? b2 : b3;
    const float* Wsrc = (l == 1) ? Wx1 : (l == 2) ? Wx2 : (l == 3) ? Wx3 : U0;

    REP8(DECLT)
    REP8(LOADT)
    REP8(DECLA)

    f32x4 cst0 = {0,0,0,0}, cst1 = {0,0,0,0};
    f32x4 hK0  = {0,0,0,0}, hK1  = {0,0,0,0};

    __fp16* hb_l  = hb16 + l * 4608;           // own buffer (4 slots x 1152 f16)
    const __fp16* hb_in = hb16 + (l > 0 ? (l - 1) * 4608 : 0);

    __syncthreads();

    for (int s = 0; s < TT + 6; ++s) {
        const int t = s - 2 * l;
        if (t >= 0 && t < TT) {
            const int sr = (t - 1) & 3, sw = t & 3;

            // own h[t-1]: B[k=unit][n=row l15]; slot (t-1)&3 (zeroed at init for t=0)
            const __fp16* hp_ = hb_l + sr * 1152 + l15 * 72 + 8 * quad;
            f16x8 hB0 = *(const f16x8*)hp_;
            f16x8 hB1 = *(const f16x8*)(hp_ + 32);

            if (t == 0) {                      // prologue: W(0)+bias inline
                if (l > 0) PREFW(0)
                else       PREFX(0)
            }

            REP8(MU0)
            REP8(MU1)

            __fp16* hw_ = hb_l + sw * 1152 + l15 * 72 + 32 * h + 4 * quad;
            const bool sv_ = (l == 3) && (t == TT - 1);
            GATES(0, acc0, acc2, acc4, acc6, cst0, sv_, hK0)
            GATES(1, acc1, acc3, acc5, acc7, cst1, sv_, hK1)

            if (t + 1 < TT) {                  // off-chain W prefetch for t+1
                if (l > 0) PREFW((t + 1) & 3)
                else       PREFX(t + 1)
            }
        }
        __syncthreads();
    }

    // dense epilogue: waves (3,h); lane holds h[511] f32 for units 32h+16q'+4quad+r, row l15
    if (l == 3) {
        float p = 0.f;
        #pragma unroll
        for (int r = 0; r < 4; ++r) {
            p += hK0[r] * Wd[32 * h + 4 * quad + r];
            p += hK1[r] * Wd[32 * h + 16 + 4 * quad + r];
        }
        p += __shfl_down(p, 32, 64);
        p += __shfl_down(p, 16, 64);
        if (lane < 16) red[h * 16 + lane] = p;
    }
    __syncthreads();
    if (wv == 6 && lane < 16) out[b0i + lane] = red[lane] + red[16 + lane] + bd[0];
}

extern "C" void kernel_launch(void* const* d_in, const int* in_sizes, int n_in,
                              void* d_out, int out_size, void* d_ws, size_t ws_size,
                              hipStream_t stream) {
    const float* x   = (const float*)d_in[0];
    const float* Wx0 = (const float*)d_in[1];
    const float* U0  = (const float*)d_in[2];
    const float* b0  = (const float*)d_in[3];
    const float* Wx1 = (const float*)d_in[4];
    const float* U1  = (const float*)d_in[5];
    const float* b1  = (const float*)d_in[6];
    const float* Wx2 = (const float*)d_in[7];
    const float* U2  = (const float*)d_in[8];
    const float* b2  = (const float*)d_in[9];
    const float* Wx3 = (const float*)d_in[10];
    const float* U3  = (const float*)d_in[11];
    const float* b3  = (const float*)d_in[12];
    const float* Wd  = (const float*)d_in[13];
    const float* bd  = (const float*)d_in[14];
    float* out = (float*)d_out;

    static const int kLds = 17952 * 4;   // 71808 B dynamic LDS
    (void)hipFuncSetAttribute((const void*)lstm_pipe,
                              hipFuncAttributeMaxDynamicSharedMemorySize, kLds);
    hipLaunchKernelGGL(lstm_pipe, dim3(64), dim3(512), kLds, stream,
                       x, Wx0, U0, b0, Wx1, U1, b1, Wx2, U2, b2, Wx3, U3, b3,
                       Wd, bd, out);
}

// Round 11
// 711.530 us; speedup vs baseline: 2.3216x; 1.0660x over previous
//
#include <hip/hip_runtime.h>
#include <stdint.h>

#define TT 512

typedef __fp16   f16x8  __attribute__((ext_vector_type(8)));
typedef float    f32x4  __attribute__((ext_vector_type(4)));
typedef __fp16   fp16x2 __attribute__((ext_vector_type(2)));
typedef uint32_t u32x2  __attribute__((ext_vector_type(2)));

__device__ __forceinline__ f32x4 mfma16(f16x8 a, f16x8 b, f32x4 c) {
    return __builtin_amdgcn_mfma_f32_16x16x32_f16(a, b, c, 0, 0, 0);
}
__device__ __forceinline__ uint32_t pkf16(float a, float b) {
    fp16x2 h = __builtin_amdgcn_cvt_pkrtz(a, b);
    return __builtin_bit_cast(uint32_t, h);
}

#define REP8(M) M(0)M(1)M(2)M(3)M(4)M(5)M(6)M(7)

// A-operand gather (weights transposed, z^T form): A[m=16T+l15][k=32F+8q+j] = SRC[k][16T+l15]
#define GA(SRC, T, F) (f16x8){ \
  (__fp16)(SRC)[(32*(F)+8*quad+0)*256 + 16*(T)+l15], \
  (__fp16)(SRC)[(32*(F)+8*quad+1)*256 + 16*(T)+l15], \
  (__fp16)(SRC)[(32*(F)+8*quad+2)*256 + 16*(T)+l15], \
  (__fp16)(SRC)[(32*(F)+8*quad+3)*256 + 16*(T)+l15], \
  (__fp16)(SRC)[(32*(F)+8*quad+4)*256 + 16*(T)+l15], \
  (__fp16)(SRC)[(32*(F)+8*quad+5)*256 + 16*(T)+l15], \
  (__fp16)(SRC)[(32*(F)+8*quad+6)*256 + 16*(T)+l15], \
  (__fp16)(SRC)[(32*(F)+8*quad+7)*256 + 16*(T)+l15] }

// Wave (l,h) owns zcols {64g + 32h + 16q' .. +15}: local j = 2g+q' -> global tile:
#define DECLT(j) f16x8 uA##j##_0, uA##j##_1, wA##j##_0, wA##j##_1; f32x4 bias##j;
#define LOADT(j) { \
  const int Tg_ = ((j)>>1)*4 + 2*h + ((j)&1); \
  uA##j##_0 = GA(Uw, Tg_, 0); uA##j##_1 = GA(Uw, Tg_, 1); \
  bias##j = (f32x4){ bw_[16*Tg_ + 4*quad + 0], bw_[16*Tg_ + 4*quad + 1], \
                     bw_[16*Tg_ + 4*quad + 2], bw_[16*Tg_ + 4*quad + 3] }; \
  if (l > 0) { wA##j##_0 = GA(Wsrc, Tg_, 0); wA##j##_1 = GA(Wsrc, Tg_, 1); } \
  else { wA##j##_0 = __builtin_bit_cast(f16x8, (f32x4){ \
           Wx0[16*Tg_+4*quad+0], Wx0[16*Tg_+4*quad+1], \
           Wx0[16*Tg_+4*quad+2], Wx0[16*Tg_+4*quad+3] }); \
         wA##j##_1 = wA##j##_0; } }

#define DECLA(j) f32x4 acc##j;
// W-side runs IN-step but its xB operands were prefetched into REGISTERS last
// step (post-gates; data lands during the barrier). The 16 MW issue immediately
// after the barrier with zero wait, covering the hB LDS-read latency (R10 had
// the accs pre-filled, leaving nothing to issue during the hB stall).
#define MW0(j) acc##j = mfma16(wA##j##_0, xBp0, bias##j);
#define MW1(j) acc##j = mfma16(wA##j##_1, xBp1, acc##j);
#define MX(j)  acc##j = bias##j + __builtin_bit_cast(f32x4, wA##j##_0) * xvp4;
// U-side: the recurrence-critical MFMAs (hB just arrived from LDS).
#define MU0(j) acc##j = mfma16(uA##j##_0, hB0, acc##j);
#define MU1(j) acc##j = mfma16(uA##j##_1, hB1, acc##j);

// Gates: trans batched (exp burst, rcp burst), tail as WHOLE-VECTOR f32x4 ops
// -> v_pk_fma_f32/v_pk_mul_f32 (halves the ~160-instr scalarized tail of R10).
#define GATES(qp, Ai, Af, Ag, Ao, CST, SAVEK, HK) { \
  f32x4 ei_, ef_, eo_; \
  _Pragma("unroll") for (int r_ = 0; r_ < 4; ++r_) { \
    ei_[r_] = __builtin_amdgcn_exp2f(-1.4426950408889634f * Ai[r_]); \
    ef_[r_] = __builtin_amdgcn_exp2f(-1.4426950408889634f * Af[r_]); \
    eo_[r_] = __builtin_amdgcn_exp2f(-1.4426950408889634f * Ao[r_]); \
  } \
  f32x4 si_, sf_, so_; \
  _Pragma("unroll") for (int r_ = 0; r_ < 4; ++r_) { \
    si_[r_] = __builtin_amdgcn_rcpf(1.0f + ei_[r_]); \
    sf_[r_] = __builtin_amdgcn_rcpf(1.0f + ef_[r_]); \
    so_[r_] = __builtin_amdgcn_rcpf(1.0f + eo_[r_]); \
  } \
  const f32x4 z4_ = {0.f, 0.f, 0.f, 0.f}; \
  f32x4 rg_ = __builtin_elementwise_max(Ag, z4_); \
  f32x4 cv_ = sf_ * CST + si_ * rg_; \
  CST = cv_; \
  f32x4 hv_ = so_ * __builtin_elementwise_max(cv_, z4_); \
  u32x2 pv_ = { pkf16(hv_[0], hv_[1]), pkf16(hv_[2], hv_[3]) }; \
  *(u32x2*)(hw_ + 16*(qp)) = pv_; \
  if (SAVEK) HK = hv_; }

// 64 blocks x 512 threads; block = 16 batch rows; 8 waves = 4 layers x 2 unit-halves.
// Skew-2 layer pipeline (layer l at t = s-2l); one barrier/step. Post-barrier order:
// hB reads issue -> W-MFMAs (reg-prefetched operands, no wait) -> U-MFMAs -> pk-gates
// -> h write -> xB register prefetch for t+1. 4-deep h slot ring per layer.
__global__ __launch_bounds__(512)
__attribute__((amdgpu_waves_per_eu(2, 2)))
void lstm_pipe(
    const float* __restrict__ x,
    const float* __restrict__ Wx0, const float* __restrict__ U0, const float* __restrict__ b0,
    const float* __restrict__ Wx1, const float* __restrict__ U1, const float* __restrict__ b1,
    const float* __restrict__ Wx2, const float* __restrict__ U2, const float* __restrict__ b2,
    const float* __restrict__ Wx3, const float* __restrict__ U3, const float* __restrict__ b3,
    const float* __restrict__ Wd,  const float* __restrict__ bd,
    float* __restrict__ out)
{
    // dwords: hbuf f16 [0,9216) | x_s f32 [9216,17920) | red f32 [17920,17952)
    extern __shared__ uint32_t smem[];
    __fp16* hb16 = (__fp16*)smem;              // [l][slot4][row 16][unit 64 pad 72]
    float*  xs   = (float*)(smem + 9216);      // [t][17]
    float*  red  = (float*)(smem + 17920);     // [2][16] epilogue partials

    const int tid  = threadIdx.x;
    const int lane = tid & 63;
    const int l15  = lane & 15;
    const int quad = lane >> 4;
    const int wv   = tid >> 6;
    const int l    = wv >> 1;                  // layer
    const int h    = wv & 1;                   // unit-half
    const int b0i  = blockIdx.x * 16;

    // ---- staging ----
    for (int i = tid; i < 9216; i += 512) smem[i] = 0;       // zero all h slots
    for (int i = tid; i < 16 * TT; i += 512) {
        int row = i >> 9, t_ = i & (TT - 1);
        xs[t_ * 17 + row] = x[(b0i + row) * TT + t_];
    }

    const float* Uw   = (l == 0) ? U0 : (l == 1) ? U1 : (l == 2) ? U2 : U3;
    const float* bw_  = (l == 0) ? b0 : (l == 1) ? b1 : (l == 2) ? b2 : b3;
    const float* Wsrc = (l == 1) ? Wx1 : (l == 2) ? Wx2 : (l == 3) ? Wx3 : U0;

    REP8(DECLT)
    REP8(LOADT)

    f32x4 cst0 = {0,0,0,0}, cst1 = {0,0,0,0};
    f32x4 hK0  = {0,0,0,0}, hK1  = {0,0,0,0};

    __fp16* hb_l  = hb16 + l * 4608;           // own buffer (4 slots x 1152 f16)
    const __fp16* hb_in = hb16 + (l > 0 ? (l - 1) * 4608 : 0);

    f16x8 xBp0 = {}, xBp1 = {};                // register-prefetched x-side operands
    float xvp = 0.f;

    __syncthreads();

    if (l == 0) xvp = xs[l15];                 // layer-0 prefetch for t=0

    for (int s = 0; s < TT + 6; ++s) {
        const int t = s - 2 * l;
        if (t >= 0 && t < TT) {
            const int sr = (t - 1) & 3, sw = t & 3;

            // own h[t-1]: issued first; latency covered by the W-MFMA burst below
            const __fp16* hp_ = hb_l + sr * 1152 + l15 * 72 + 8 * quad;
            f16x8 hB0 = *(const f16x8*)hp_;
            f16x8 hB1 = *(const f16x8*)(hp_ + 32);

            REP8(DECLA)
            if (l > 0) { REP8(MW0) REP8(MW1) }
            else       { f32x4 xvp4 = {xvp, xvp, xvp, xvp}; REP8(MX) }
            REP8(MU0)
            REP8(MU1)

            __fp16* hw_ = hb_l + sw * 1152 + l15 * 72 + 32 * h + 4 * quad;
            const bool sv_ = (l == 3) && (t == TT - 1);
            GATES(0, acc0, acc2, acc4, acc6, cst0, sv_, hK0)
            GATES(1, acc1, acc3, acc5, acc7, cst1, sv_, hK1)

            if (t + 1 < TT) {                  // operand prefetch for t+1 (lands over barrier)
                if (l > 0) {
                    const __fp16* xp_ = hb_in + ((t + 1) & 3) * 1152 + l15 * 72 + 8 * quad;
                    xBp0 = *(const f16x8*)xp_;
                    xBp1 = *(const f16x8*)(xp_ + 32);
                } else {
                    xvp = xs[(t + 1) * 17 + l15];
                }
            }
        } else if (t == -1 && l > 0) {
            // pipeline fill: prefetch x-side operands for t=0 (producer wrote slot 0 at s-2)
            const __fp16* xp_ = hb_in + l15 * 72 + 8 * quad;
            xBp0 = *(const f16x8*)xp_;
            xBp1 = *(const f16x8*)(xp_ + 32);
        }
        __syncthreads();
    }

    // dense epilogue: waves (3,h); lane holds h[511] f32 for units 32h+16q'+4quad+r, row l15
    if (l == 3) {
        float p = 0.f;
        #pragma unroll
        for (int r = 0; r < 4; ++r) {
            p += hK0[r] * Wd[32 * h + 4 * quad + r];
            p += hK1[r] * Wd[32 * h + 16 + 4 * quad + r];
        }
        p += __shfl_down(p, 32, 64);
        p += __shfl_down(p, 16, 64);
        if (lane < 16) red[h * 16 + lane] = p;
    }
    __syncthreads();
    if (wv == 6 && lane < 16) out[b0i + lane] = red[lane] + red[16 + lane] + bd[0];
}

extern "C" void kernel_launch(void* const* d_in, const int* in_sizes, int n_in,
                              void* d_out, int out_size, void* d_ws, size_t ws_size,
                              hipStream_t stream) {
    const float* x   = (const float*)d_in[0];
    const float* Wx0 = (const float*)d_in[1];
    const float* U0  = (const float*)d_in[2];
    const float* b0  = (const float*)d_in[3];
    const float* Wx1 = (const float*)d_in[4];
    const float* U1  = (const float*)d_in[5];
    const float* b1  = (const float*)d_in[6];
    const float* Wx2 = (const float*)d_in[7];
    const float* U2  = (const float*)d_in[8];
    const float* b2  = (const float*)d_in[9];
    const float* Wx3 = (const float*)d_in[10];
    const float* U3  = (const float*)d_in[11];
    const float* b3  = (const float*)d_in[12];
    const float* Wd  = (const float*)d_in[13];
    const float* bd  = (const float*)d_in[14];
    float* out = (float*)d_out;

    static const int kLds = 17952 * 4;   // 71808 B dynamic LDS
    (void)hipFuncSetAttribute((const void*)lstm_pipe,
                              hipFuncAttributeMaxDynamicSharedMemorySize, kLds);
    hipLaunchKernelGGL(lstm_pipe, dim3(64), dim3(512), kLds, stream,
                       x, Wx0, U0, b0, Wx1, U1, b1, Wx2, U2, b2, Wx3, U3, b3,
                       Wd, bd, out);
}

// Round 12
// 692.283 us; speedup vs baseline: 2.3861x; 1.0278x over previous
//
#include <hip/hip_runtime.h>
#include <stdint.h>

#define TT 512

typedef __fp16   f16x8  __attribute__((ext_vector_type(8)));
typedef float    f32x4  __attribute__((ext_vector_type(4)));
typedef __fp16   fp16x2 __attribute__((ext_vector_type(2)));
typedef uint32_t u32x2  __attribute__((ext_vector_type(2)));

__device__ __forceinline__ f32x4 mfma16(f16x8 a, f16x8 b, f32x4 c) {
    return __builtin_amdgcn_mfma_f32_16x16x32_f16(a, b, c, 0, 0, 0);
}
__device__ __forceinline__ uint32_t pkf16(float a, float b) {
    fp16x2 h = __builtin_amdgcn_cvt_pkrtz(a, b);
    return __builtin_bit_cast(uint32_t, h);
}

#define REP8(M) M(0)M(1)M(2)M(3)M(4)M(5)M(6)M(7)

// A-operand gather (weights transposed, z^T form): A[m=16T+l15][k=32F+8q+j] = SRC[k][16T+l15]
#define GA(SRC, T, F) (f16x8){ \
  (__fp16)(SRC)[(32*(F)+8*quad+0)*256 + 16*(T)+l15], \
  (__fp16)(SRC)[(32*(F)+8*quad+1)*256 + 16*(T)+l15], \
  (__fp16)(SRC)[(32*(F)+8*quad+2)*256 + 16*(T)+l15], \
  (__fp16)(SRC)[(32*(F)+8*quad+3)*256 + 16*(T)+l15], \
  (__fp16)(SRC)[(32*(F)+8*quad+4)*256 + 16*(T)+l15], \
  (__fp16)(SRC)[(32*(F)+8*quad+5)*256 + 16*(T)+l15], \
  (__fp16)(SRC)[(32*(F)+8*quad+6)*256 + 16*(T)+l15], \
  (__fp16)(SRC)[(32*(F)+8*quad+7)*256 + 16*(T)+l15] }

// Wave (l,h) owns zcols {64g + 32h + 16q' .. +15}: local j = 2g+q' -> global tile:
#define DECLT(j) f16x8 uA##j##_0, uA##j##_1, wA##j##_0, wA##j##_1; f32x4 bias##j;
#define LOADT(j) { \
  const int Tg_ = ((j)>>1)*4 + 2*h + ((j)&1); \
  uA##j##_0 = GA(Uw, Tg_, 0); uA##j##_1 = GA(Uw, Tg_, 1); \
  bias##j = (f32x4){ bw_[16*Tg_ + 4*quad + 0], bw_[16*Tg_ + 4*quad + 1], \
                     bw_[16*Tg_ + 4*quad + 2], bw_[16*Tg_ + 4*quad + 3] }; \
  if (l > 0) { wA##j##_0 = GA(Wsrc, Tg_, 0); wA##j##_1 = GA(Wsrc, Tg_, 1); } \
  else { wA##j##_0 = __builtin_bit_cast(f16x8, (f32x4){ \
           Wx0[16*Tg_+4*quad+0], Wx0[16*Tg_+4*quad+1], \
           Wx0[16*Tg_+4*quad+2], Wx0[16*Tg_+4*quad+3] }); \
         wA##j##_1 = wA##j##_0; } }

// MFMA segment: W-side first (xBp register-prefetched, bias rides C), U-side last.
#define MW0(j) acc##j = mfma16(wA##j##_0, xBp0, bias##j);
#define MW1(j) acc##j = mfma16(wA##j##_1, xBp1, acc##j);
#define MX(j)  acc##j = bias##j + __builtin_bit_cast(f32x4, wA##j##_0) * xvp4;
#define MU0(j) acc##j = mfma16(uA##j##_0, hB0, acc##j);
#define MU1(j) acc##j = mfma16(uA##j##_1, hB1, acc##j);

#define MFMA_SEG(t_) { \
  const __fp16* hp_ = hb_l + (((t_)-1)&3)*1152 + l15*72 + 8*quad; \
  f16x8 hB0 = *(const f16x8*)hp_; \
  f16x8 hB1 = *(const f16x8*)(hp_ + 32); \
  if (l > 0) { REP8(MW0) REP8(MW1) } \
  else       { f32x4 xvp4 = {xvp, xvp, xvp, xvp}; REP8(MX) } \
  REP8(MU0) \
  REP8(MU1) }

// Gates: trans batched (exp burst, rcp burst), vector f32x4 tail -> pk ops.
#define GATES(qp, Ai, Af, Ag, Ao, CST, SAVEK, HK) { \
  f32x4 ei_, ef_, eo_; \
  _Pragma("unroll") for (int r_ = 0; r_ < 4; ++r_) { \
    ei_[r_] = __builtin_amdgcn_exp2f(-1.4426950408889634f * Ai[r_]); \
    ef_[r_] = __builtin_amdgcn_exp2f(-1.4426950408889634f * Af[r_]); \
    eo_[r_] = __builtin_amdgcn_exp2f(-1.4426950408889634f * Ao[r_]); \
  } \
  f32x4 si_, sf_, so_; \
  _Pragma("unroll") for (int r_ = 0; r_ < 4; ++r_) { \
    si_[r_] = __builtin_amdgcn_rcpf(1.0f + ei_[r_]); \
    sf_[r_] = __builtin_amdgcn_rcpf(1.0f + ef_[r_]); \
    so_[r_] = __builtin_amdgcn_rcpf(1.0f + eo_[r_]); \
  } \
  const f32x4 z4_ = {0.f, 0.f, 0.f, 0.f}; \
  f32x4 rg_ = __builtin_elementwise_max(Ag, z4_); \
  f32x4 cv_ = sf_ * CST + si_ * rg_; \
  CST = cv_; \
  f32x4 hv_ = so_ * __builtin_elementwise_max(cv_, z4_); \
  u32x2 pv_ = { pkf16(hv_[0], hv_[1]), pkf16(hv_[2], hv_[3]) }; \
  *(u32x2*)(hw_ + 16*(qp)) = pv_; \
  if (SAVEK) HK = hv_; }

#define GATE_SEG(tg_, SV_) { \
  __fp16* hw_ = hb_l + ((tg_)&3)*1152 + l15*72 + 32*h + 4*quad; \
  GATES(0, acc0, acc2, acc4, acc6, cst0, SV_, hK0) \
  GATES(1, acc1, acc3, acc5, acc7, cst1, SV_, hK1) }

// 64 blocks x 512 threads; block = 16 batch rows; 8 waves = 4 layers x 2 unit-halves.
// ANTI-PHASE layer split (R12): layers {0,1} = phase A (MFMA seg1, gates seg2),
// layers {2,3} = phase B (gates seg1, MFMA seg2). SIMD wave pairs are (l, l+2) =
// one A + one B -> every SIMD always has one wave on MFMA pipe + one on trans pipe
// instead of barrier-locked duplication (R7-R11 stuck ~3050 cyc/step, pipes <16% busy).
// Two barriers/step; skew-2 (layer l at t = s-2l); 4-slot h ring per layer.
__global__ __launch_bounds__(512)
__attribute__((amdgpu_waves_per_eu(2, 2)))
void lstm_phase(
    const float* __restrict__ x,
    const float* __restrict__ Wx0, const float* __restrict__ U0, const float* __restrict__ b0,
    const float* __restrict__ Wx1, const float* __restrict__ U1, const float* __restrict__ b1,
    const float* __restrict__ Wx2, const float* __restrict__ U2, const float* __restrict__ b2,
    const float* __restrict__ Wx3, const float* __restrict__ U3, const float* __restrict__ b3,
    const float* __restrict__ Wd,  const float* __restrict__ bd,
    float* __restrict__ out)
{
    // dwords: hbuf f16 [0,9216) | x_s f32 [9216,17920) | red f32 [17920,17952)
    extern __shared__ uint32_t smem[];
    __fp16* hb16 = (__fp16*)smem;              // [l][slot4][row 16][unit 64 pad 72]
    float*  xs   = (float*)(smem + 9216);      // [t][17]
    float*  red  = (float*)(smem + 17920);     // [2][16] epilogue partials

    const int tid  = threadIdx.x;
    const int lane = tid & 63;
    const int l15  = lane & 15;
    const int quad = lane >> 4;
    const int wv   = tid >> 6;
    const int l    = wv >> 1;                  // layer
    const int h    = wv & 1;                   // unit-half
    const int b0i  = blockIdx.x * 16;
    const bool phA = (l < 2);

    // ---- staging ----
    for (int i = tid; i < 9216; i += 512) smem[i] = 0;       // zero all h slots
    for (int i = tid; i < 16 * TT; i += 512) {
        int row = i >> 9, t_ = i & (TT - 1);
        xs[t_ * 17 + row] = x[(b0i + row) * TT + t_];
    }

    const float* Uw   = (l == 0) ? U0 : (l == 1) ? U1 : (l == 2) ? U2 : U3;
    const float* bw_  = (l == 0) ? b0 : (l == 1) ? b1 : (l == 2) ? b2 : b3;
    const float* Wsrc = (l == 1) ? Wx1 : (l == 2) ? Wx2 : (l == 3) ? Wx3 : U0;

    REP8(DECLT)
    REP8(LOADT)

    f32x4 acc0, acc1, acc2, acc3, acc4, acc5, acc6, acc7;    // persist across barriers
    f32x4 cst0 = {0,0,0,0}, cst1 = {0,0,0,0};
    f32x4 hK0  = {0,0,0,0}, hK1  = {0,0,0,0};

    __fp16* hb_l  = hb16 + l * 4608;           // own buffer (4 slots x 1152 f16)
    const __fp16* hb_in = hb16 + (l > 0 ? (l - 1) * 4608 : 0);

    f16x8 xBp0 = {}, xBp1 = {};                // register-prefetched x-side operands
    float xvp = 0.f;

    __syncthreads();

    if (l == 0) xvp = xs[l15];                 // layer-0 prefetch for t=0

    for (int s = 0; s < TT + 8; ++s) {
        // ---------------- SEG1 ----------------
        if (phA) {
            const int t = s - 2 * l;
            if (t >= 0 && t < TT) MFMA_SEG(t)
        } else {
            // prefetch first (latency overlaps gate compute below)
            const int tm = s - 2 * l;          // step whose MFMA runs in SEG2
            if (tm >= 0 && tm < TT) {
                const __fp16* xp_ = hb_in + (tm & 3) * 1152 + l15 * 72 + 8 * quad;
                xBp0 = *(const f16x8*)xp_;
                xBp1 = *(const f16x8*)(xp_ + 32);
            }
            const int tg = s - 1 - 2 * l;      // gates of last interval's accs
            if (tg >= 0 && tg < TT) {
                const bool sv_ = (l == 3) && (tg == TT - 1);
                GATE_SEG(tg, sv_)
            }
        }
        __syncthreads();
        // ---------------- SEG2 ----------------
        if (phA) {
            // prefetch first
            const int tn = s + 1 - 2 * l;      // step whose MFMA runs next SEG1
            if (tn >= 0 && tn < TT) {
                if (l > 0) {
                    const __fp16* xp_ = hb_in + (tn & 3) * 1152 + l15 * 72 + 8 * quad;
                    xBp0 = *(const f16x8*)xp_;
                    xBp1 = *(const f16x8*)(xp_ + 32);
                } else {
                    xvp = xs[tn * 17 + l15];
                }
            }
            const int t = s - 2 * l;
            if (t >= 0 && t < TT) GATE_SEG(t, false)
        } else {
            const int t = s - 2 * l;
            if (t >= 0 && t < TT) MFMA_SEG(t)
        }
        __syncthreads();
    }

    // dense epilogue: waves (3,h); lane holds h[511] f32 for units 32h+16q'+4quad+r, row l15
    if (l == 3) {
        float p = 0.f;
        #pragma unroll
        for (int r = 0; r < 4; ++r) {
            p += hK0[r] * Wd[32 * h + 4 * quad + r];
            p += hK1[r] * Wd[32 * h + 16 + 4 * quad + r];
        }
        p += __shfl_down(p, 32, 64);
        p += __shfl_down(p, 16, 64);
        if (lane < 16) red[h * 16 + lane] = p;
    }
    __syncthreads();
    if (wv == 6 && lane < 16) out[b0i + lane] = red[lane] + red[16 + lane] + bd[0];
}

extern "C" void kernel_launch(void* const* d_in, const int* in_sizes, int n_in,
                              void* d_out, int out_size, void* d_ws, size_t ws_size,
                              hipStream_t stream) {
    const float* x   = (const float*)d_in[0];
    const float* Wx0 = (const float*)d_in[1];
    const float* U0  = (const float*)d_in[2];
    const float* b0  = (const float*)d_in[3];
    const float* Wx1 = (const float*)d_in[4];
    const float* U1  = (const float*)d_in[5];
    const float* b1  = (const float*)d_in[6];
    const float* Wx2 = (const float*)d_in[7];
    const float* U2  = (const float*)d_in[8];
    const float* b2  = (const float*)d_in[9];
    const float* Wx3 = (const float*)d_in[10];
    const float* U3  = (const float*)d_in[11];
    const float* b3  = (const float*)d_in[12];
    const float* Wd  = (const float*)d_in[13];
    const float* bd  = (const float*)d_in[14];
    float* out = (float*)d_out;

    static const int kLds = 17952 * 4;   // 71808 B dynamic LDS
    (void)hipFuncSetAttribute((const void*)lstm_phase,
                              hipFuncAttributeMaxDynamicSharedMemorySize, kLds);
    hipLaunchKernelGGL(lstm_phase, dim3(64), dim3(512), kLds, stream,
                       x, Wx0, U0, b0, Wx1, U1, b1, Wx2, U2, b2, Wx3, U3, b3,
                       Wd, bd, out);
}